// Round 15
// baseline (361.301 us; speedup 1.0000x reference)
//
#include <hip/hip_runtime.h>

typedef _Float16 f16;
typedef _Float16 f16x8 __attribute__((ext_vector_type(8)));
typedef _Float16 f16x4 __attribute__((ext_vector_type(4)));
typedef float f32x4 __attribute__((ext_vector_type(4)));

#define DEVI __device__ __forceinline__

constexpr int B_ = 4, C_ = 256, N_ = 4096;

#define MFMAH(a, b, c) __builtin_amdgcn_mfma_f32_16x16x32_f16((a), (b), (c), 0, 0, 0)

DEVI void gload16(const void* g, void* l) {
  __builtin_amdgcn_global_load_lds((const __attribute__((address_space(1))) void*)g,
                                   (__attribute__((address_space(3))) void*)l, 16, 0, 0);
}

// broadcast per-row value (rows 4g+r live in lanes of group g) to O layout (row idx = l15)
DEVI float bcast_row(float v0, float v1, float v2, float v3, int l15) {
  int src = (l15 >> 2) << 4;
  float a0 = __shfl(v0, src, 64);
  float a1 = __shfl(v1, src, 64);
  float a2 = __shfl(v2, src, 64);
  float a3 = __shfl(v3, src, 64);
  float x0 = (l15 & 1) ? a1 : a0;
  float x1 = (l15 & 1) ? a3 : a2;
  return (l15 & 2) ? x1 : x0;
}

// ---------------- kernel 0: weight conversion to fp16 ----------------
__global__ __launch_bounds__(256, 1) void prep_weights(
    const float* __restrict__ wq, const float* __restrict__ wk,
    const float* __restrict__ wv, const float* __restrict__ wo,
    f16* __restrict__ wqh, f16* __restrict__ wkh,
    f16* __restrict__ wvh, f16* __restrict__ woh) {
  int idx = blockIdx.x * 256 + threadIdx.x;
  wqh[idx] = (f16)wq[idx];
  wkh[idx] = (f16)wk[idx];
  wvh[idx] = (f16)wv[idx];
  woh[idx] = (f16)wo[idx];
}

// ---------------- kernel 1: K (fp16, transposed) and V projections ----------------
__global__ __launch_bounds__(256, 2) void proj_kv(
    const float* __restrict__ ctx, const float* __restrict__ bk, const float* __restrict__ bv,
    const f16* __restrict__ wkh, const f16* __restrict__ wvh,
    f16* __restrict__ KTh, f16* __restrict__ Vg) {
  const int blk = blockIdx.x;
  const int b = blk & 3;
  const int j0 = (blk >> 2) << 6;
  const int tid = threadIdx.x;
  const int lane = tid & 63;
  const int w = tid >> 6;
  const int l15 = lane & 15;
  const int g = lane >> 4;

  __shared__ alignas(16) f16 ldsC[64 * 256];

  // stage ctx^T (fp16) into LDS [j][c], swizzled
  {
    const float* cb = ctx + (size_t)b * C_ * N_ + j0;
    #pragma unroll
    for (int it = 0; it < 16; ++it) {
      int idx = it * 256 + tid;
      int c = idx >> 4;
      int j4 = (idx & 15) << 2;
      float4 f = *(const float4*)(cb + (size_t)c * N_ + j4);
      float vv[4] = {f.x, f.y, f.z, f.w};
      #pragma unroll
      for (int e = 0; e < 4; ++e) {
        int j = j4 + e;
        int uidx = j * 256 + ((((c >> 3) ^ (j & 7))) << 3) + (c & 7);
        ldsC[uidx] = (f16)vv[e];
      }
    }
  }
  __syncthreads();

  const int jloc = 16 * w + l15;
  f16x8 ch[8];
  #pragma unroll
  for (int ks = 0; ks < 8; ++ks)
    ch[ks] = *(const f16x8*)&ldsC[jloc * 256 + (((g + 4 * ks) ^ (jloc & 7)) << 3)];

  #pragma unroll 4
  for (int mt = 0; mt < 16; ++mt) {
    f32x4 ka = {0, 0, 0, 0}, va = {0, 0, 0, 0};
    #pragma unroll
    for (int ks = 0; ks < 8; ++ks) {
      int aoff = (16 * mt + l15) * 256 + 8 * g + 32 * ks;
      f16x8 ah = *(const f16x8*)(wkh + aoff);
      f16x8 av = *(const f16x8*)(wvh + aoff);
      ka = MFMAH(ah, ch[ks], ka);
      va = MFMAH(av, ch[ks], va);
    }
    int c0 = 16 * mt + 4 * g;
    float4 bk4 = *(const float4*)(bk + c0);
    float4 bv4 = *(const float4*)(bv + c0);
    f16x4 h4;
    #pragma unroll
    for (int r = 0; r < 4; ++r) h4[r] = (f16)(ka[r] + ((const float*)&bk4)[r]);
    *(f16x4*)(KTh + ((size_t)b * N_ + j0 + jloc) * C_ + c0) = h4;
    #pragma unroll
    for (int r = 0; r < 4; ++r) {
      float vv = va[r] + ((const float*)&bv4)[r];
      Vg[((size_t)b * C_ + c0 + r) * N_ + j0 + jloc] = (f16)vv;
    }
  }
}

// ---- async staging helpers (512 threads): linear LDS dest, inverse-swizzled src ----
DEVI void stageK(const f16* khg, int kv0, f16* ldsK, int tid) {
  #pragma unroll
  for (int t = 0; t < 4; ++t) {
    int L = t * 512 + tid;
    int j = L >> 5, s = L & 31;
    const f16* src = khg + (size_t)(kv0 + j) * C_ + ((s ^ (j & 7)) << 3);
    gload16(src, ldsK + (size_t)L * 8);
  }
}
DEVI void stageV(const f16* vg, int kv0, f16* ldsV, int tid) {
  #pragma unroll
  for (int t = 0; t < 4; ++t) {
    int L = t * 512 + tid;
    int c = L >> 3, sl = L & 7;
    const f16* src = vg + (size_t)c * N_ + kv0 + ((sl ^ (c & 7)) << 3);
    gload16(src, ldsV + (size_t)L * 8);
  }
}

// ---------------- kernel 2: fused Q-proj + flash attention + O-proj + residual ----------------
// 512 threads: 8 waves. Waves w and w+4 own the same 16 query rows; they duplicate
// QK+softmax (deterministic) and split PV/O-proj/output by channel half h = w>>2.
__global__ __launch_bounds__(512, 2) void attn_fused(
    const float* __restrict__ x, const float* __restrict__ bq, const float* __restrict__ bo,
    const f16* __restrict__ wqh, const f16* __restrict__ woh,
    const f16* __restrict__ KTh, const f16* __restrict__ Vg,
    float* __restrict__ out) {
  const int blk = blockIdx.x;
  const int b = (blk & 7) >> 1;                        // XCD x -> batch x>>1 (K/V fits L2)
  const int i0 = (((blk >> 3) << 1) | (blk & 1)) << 6;
  const int tid = threadIdx.x;
  const int lane = tid & 63;
  const int w = tid >> 6;          // 0..7
  const int h = w >> 2;            // channel half
  const int rg = w & 3;            // row group
  const int l15 = lane & 15;
  const int g = lane >> 4;

  __shared__ alignas(16) char smem[149504];
  f16* ldsK0 = (f16*)smem;              // K tile dbuf 0 (prologue: x/Q ; epilogue: O)
  f16* ldsK1 = (f16*)(smem + 32768);    // K tile dbuf 1
  f16* ldsV0 = (f16*)(smem + 65536);    // V tile dbuf 0
  f16* ldsV1 = (f16*)(smem + 98304);    // V tile dbuf 1
  f16* ldsPT = (f16*)(smem + 131072);   // per-wave P^T [16 rows][72-stride]

  // ---- stage x^T fp16 into ldsK0 [i][c] swizzled (512 threads -> 8 iters)
  {
    const float* xb = x + (size_t)b * C_ * N_ + i0;
    #pragma unroll
    for (int it = 0; it < 8; ++it) {
      int idx = it * 512 + tid;
      int c = idx >> 4;
      int i4 = (idx & 15) << 2;
      float4 f = *(const float4*)(xb + (size_t)c * N_ + i4);
      float vv[4] = {f.x, f.y, f.z, f.w};
      #pragma unroll
      for (int e = 0; e < 4; ++e) {
        int i = i4 + e;
        int uidx = i * 256 + ((((c >> 3) ^ (i & 7))) << 3) + (c & 7);
        ldsK0[uidx] = (f16)vv[e];
      }
    }
  }
  __syncthreads();

  const int iloc = 16 * rg + l15;

  f16x8 xh[8];
  #pragma unroll
  for (int ks = 0; ks < 8; ++ks)
    xh[ks] = *(const f16x8*)&ldsK0[iloc * 256 + (((g + 4 * ks) ^ (iloc & 7)) << 3)];

  // Q = wq x + bq — each wave computes its channel half (mt = 8h..8h+7)
  f32x4 qd[8];
  #pragma unroll
  for (int mtl = 0; mtl < 8; ++mtl) {
    int mt = 8 * h + mtl;
    f32x4 a1 = {0, 0, 0, 0};
    #pragma unroll
    for (int ks = 0; ks < 8; ++ks) {
      f16x8 ah = *(const f16x8*)(wqh + (16 * mt + l15) * 256 + 8 * g + 32 * ks);
      a1 = MFMAH(ah, xh[ks], a1);
    }
    int c0 = 16 * mt + 4 * g;
    float4 bq4 = *(const float4*)(bq + c0);
    #pragma unroll
    for (int r = 0; r < 4; ++r) qd[mtl][r] = a1[r] + ((const float*)&bq4)[r];
  }
  __syncthreads();  // done reading x

  // write Q fp16 transposed [i][c] (swizzled) — halves are disjoint in c
  #pragma unroll
  for (int mtl = 0; mtl < 8; ++mtl) {
    int c0 = 16 * (8 * h + mtl) + 4 * g;
    f16x4 h4;
    #pragma unroll
    for (int r = 0; r < 4; ++r) h4[r] = (f16)qd[mtl][r];
    *(f16x4*)&ldsK0[iloc * 256 + ((((c0 >> 3) ^ (iloc & 7))) << 3) + (c0 & 7)] = h4;
  }
  __syncthreads();

  f16x8 qh[8];  // full-C Q fragments for this wave's 16 rows
  #pragma unroll
  for (int ks = 0; ks < 8; ++ks)
    qh[ks] = *(const f16x8*)&ldsK0[iloc * 256 + (((g + 4 * ks) ^ (iloc & 7)) << 3)];
  __syncthreads();  // all waves done reading Q before staging overwrites

  const f16* khg = KTh + (size_t)b * N_ * C_;
  const f16* vg = Vg + (size_t)b * C_ * N_;

  float mrun[4] = {-1e30f, -1e30f, -1e30f, -1e30f};
  float lrun[4] = {0, 0, 0, 0};
  f32x4 oacc[8];
  #pragma unroll
  for (int mtl = 0; mtl < 8; ++mtl) oacc[mtl] = (f32x4){0, 0, 0, 0};

  stageK(khg, 0, ldsK0, tid);
  stageV(vg, 0, ldsV0, tid);
  __syncthreads();  // drain tile 0

  for (int t = 0; t < 64; ++t) {
    const int kv0 = t << 6;
    f16* Kc = (t & 1) ? ldsK1 : ldsK0;
    f16* Vc = (t & 1) ? ldsV1 : ldsV0;
    f16* Kn = (t & 1) ? ldsK0 : ldsK1;
    f16* Vn = (t & 1) ? ldsV0 : ldsV1;

    // issue next-tile staging FIRST: hides under this whole iteration
    if (t < 63) {
      stageK(khg, kv0 + 64, Kn, tid);
      stageV(vg, kv0 + 64, Vn, tid);
    }

    // ---- S = Q K (full 64 keys; duplicated across the channel-half pair)
    f32x4 s1[4];
    #pragma unroll
    for (int nt = 0; nt < 4; ++nt) s1[nt] = (f32x4){0, 0, 0, 0};
    #pragma unroll
    for (int ks = 0; ks < 8; ++ks) {
      f16x8 bh[4];
      #pragma unroll
      for (int nt = 0; nt < 4; ++nt) {
        int j = 16 * nt + l15;
        bh[nt] = *(const f16x8*)&Kc[j * 256 + (((g + 4 * ks) ^ (j & 7)) << 3)];
      }
      #pragma unroll
      for (int nt = 0; nt < 4; ++nt) s1[nt] = MFMAH(qh[ks], bh[nt], s1[nt]);
    }

    // ---- online softmax with defer-rescale (THR=6); identical in both half-waves
    float tm[4];
    #pragma unroll
    for (int r = 0; r < 4; ++r) {
      tm[r] = fmaxf(fmaxf(s1[0][r], s1[1][r]), fmaxf(s1[2][r], s1[3][r]));
      #pragma unroll
      for (int msk = 1; msk < 16; msk <<= 1) tm[r] = fmaxf(tm[r], __shfl_xor(tm[r], msk));
    }
    bool grow = (tm[0] > mrun[0] + 6.f) | (tm[1] > mrun[1] + 6.f) |
                (tm[2] > mrun[2] + 6.f) | (tm[3] > mrun[3] + 6.f);
    float sc[4] = {1.f, 1.f, 1.f, 1.f};
    int need = __any((int)grow);
    if (need) {
      #pragma unroll
      for (int r = 0; r < 4; ++r) {
        float mn = fmaxf(mrun[r], tm[r]);
        sc[r] = __expf(mrun[r] - mn);
        mrun[r] = mn;
      }
      float fsc = bcast_row(sc[0], sc[1], sc[2], sc[3], l15);
      #pragma unroll
      for (int mtl = 0; mtl < 8; ++mtl) oacc[mtl] *= fsc;
    }
    float rs[4] = {0, 0, 0, 0};
    #pragma unroll
    for (int nt = 0; nt < 4; ++nt) {
      #pragma unroll
      for (int r = 0; r < 4; ++r) {
        float p = __expf(s1[nt][r] - mrun[r]);
        s1[nt][r] = p;
        rs[r] += p;
      }
    }
    #pragma unroll
    for (int r = 0; r < 4; ++r) {
      #pragma unroll
      for (int msk = 1; msk < 16; msk <<= 1) rs[r] += __shfl_xor(rs[r], msk);
      lrun[r] = need ? lrun[r] * sc[r] + rs[r] : lrun[r] + rs[r];
    }

    // ---- P^T into per-wave buffer (stride 72) — wave-local, no barrier
    #pragma unroll
    for (int nt = 0; nt < 4; ++nt) {
      int jcol = 16 * nt + l15;
      #pragma unroll
      for (int r = 0; r < 4; ++r) ldsPT[w * 1152 + (4 * g + r) * 72 + jcol] = (f16)s1[nt][r];
    }
    f16x8 pb[2];
    #pragma unroll
    for (int ks2 = 0; ks2 < 2; ++ks2)
      pb[ks2] = *(const f16x8*)&ldsPT[w * 1152 + l15 * 72 + 8 * (g + 4 * ks2)];

    // ---- PV: O += V P^T for this wave's channel half
    #pragma unroll
    for (int ks2 = 0; ks2 < 2; ++ks2) {
      #pragma unroll
      for (int mtl = 0; mtl < 8; ++mtl) {
        int c = 16 * (8 * h + mtl) + l15;
        f16x8 va = *(const f16x8*)&Vc[c * 64 + (((g + 4 * ks2) ^ (c & 7)) << 3)];
        oacc[mtl] = MFMAH(va, pb[ks2], oacc[mtl]);
      }
    }

    __syncthreads();  // single barrier/tile: cur bufs free + next-tile loads drained
  }

  // ---- normalize
  {
    float inv[4];
    #pragma unroll
    for (int r = 0; r < 4; ++r) inv[r] = 1.0f / lrun[r];
    float fi = bcast_row(inv[0], inv[1], inv[2], inv[3], l15);
    #pragma unroll
    for (int mtl = 0; mtl < 8; ++mtl) oacc[mtl] *= fi;
  }
  // ---- O (fp16) into ldsK0 [i][c] swizzled (each wave writes its c-half)
  #pragma unroll
  for (int mtl = 0; mtl < 8; ++mtl) {
    int c0 = 16 * (8 * h + mtl) + 4 * g;
    f16x4 h4;
    #pragma unroll
    for (int r = 0; r < 4; ++r) h4[r] = (f16)oacc[mtl][r];
    *(f16x4*)&ldsK0[iloc * 256 + ((((c0 >> 3) ^ (iloc & 7))) << 3) + (c0 & 7)] = h4;
  }
  __syncthreads();
  // ---- final projection + bias + residual (each wave its mt-half)
  f32x4 facc[8];
  #pragma unroll
  for (int mtl = 0; mtl < 8; ++mtl) facc[mtl] = (f32x4){0, 0, 0, 0};
  #pragma unroll
  for (int ks = 0; ks < 8; ++ks) {
    f16x8 ob = *(const f16x8*)&ldsK0[iloc * 256 + (((g + 4 * ks) ^ (iloc & 7)) << 3)];
    #pragma unroll
    for (int mtl = 0; mtl < 8; ++mtl) {
      f16x8 ah = *(const f16x8*)(woh + (16 * (8 * h + mtl) + l15) * 256 + 8 * g + 32 * ks);
      facc[mtl] = MFMAH(ah, ob, facc[mtl]);
    }
  }
  const int ig = i0 + iloc;
  #pragma unroll
  for (int mtl = 0; mtl < 8; ++mtl) {
    int c0 = 16 * (8 * h + mtl) + 4 * g;
    float4 bo4 = *(const float4*)(bo + c0);
    #pragma unroll
    for (int r = 0; r < 4; ++r) {
      size_t off = ((size_t)b * C_ + c0 + r) * N_ + ig;
      out[off] = facc[mtl][r] + ((const float*)&bo4)[r] + x[off];
    }
  }
}

extern "C" void kernel_launch(void* const* d_in, const int* in_sizes, int n_in,
                              void* d_out, int out_size, void* d_ws, size_t ws_size,
                              hipStream_t stream) {
  const float* x = (const float*)d_in[0];
  const float* ctx = (const float*)d_in[1];
  const float* wq = (const float*)d_in[2];
  const float* bq = (const float*)d_in[3];
  const float* wk = (const float*)d_in[4];
  const float* bk = (const float*)d_in[5];
  const float* wv = (const float*)d_in[6];
  const float* bv = (const float*)d_in[7];
  const float* wo = (const float*)d_in[8];
  const float* bo = (const float*)d_in[9];
  float* out = (float*)d_out;

  f16* ws = (f16*)d_ws;
  f16* wqh = ws;
  f16* wkh = wqh + 65536;
  f16* wvh = wkh + 65536;
  f16* woh = wvh + 65536;
  f16* KTh = woh + 65536;
  f16* Vg = KTh + (size_t)B_ * N_ * C_;

  prep_weights<<<256, 256, 0, stream>>>(wq, wk, wv, wo, wqh, wkh, wvh, woh);
  proj_kv<<<256, 256, 0, stream>>>(ctx, bk, bv, wkh, wvh, KTh, Vg);
  attn_fused<<<256, 512, 0, stream>>>(x, bq, bo, wqh, woh, KTh, Vg, out);
}